// Round 12
// baseline (221.639 us; speedup 1.0000x reference)
//
#include <hip/hip_runtime.h>
#include <stdint.h>

// RelationalNetwork: B=8, C=64, O=256, TE=128, GT=FP=256, A=32
// v12 = v11 grid (1024 uniform blocks) + LDS-traffic-halving wave split:
//   k_pre : W2/W3 transpose->bf16, summed:=0, U/V precompute (pipelined)
//   k_fuse: 256 pairs/block, h1 built ONCE into LDS[256][256] (128KiB).
//           Both GEMMs 2M x 4N wave grid (wave = 128 pairs x 64 cols):
//           activation operand from LDS (64KB/wave, half of v11), weight
//           slices from L2 with 2-deep prefetch (v11-GEMM2-proven ratio).
//           GEMM1 swapped mfma(W2,h1) -> h2^T, b64 scatter; GEMM2 normal;
//           colsum -> atomicAdd summed.
//   k_tail: 8 blocks x 1024 thr; leftover 128 pairs + f_phi (unchanged).

#define NPAIR 32896   // k_fuse covers 32768, k_tail the last 128

using short8  = __attribute__((ext_vector_type(8))) short;
using float4v = __attribute__((ext_vector_type(4))) float;

__device__ __forceinline__ float asf(unsigned u) {
    union { unsigned u; float f; } c; c.u = u; return c.f;
}
__device__ __forceinline__ unsigned short f2bf(float f) {
    union { float f; unsigned u; } c; c.f = f;
    unsigned u = c.u;
    u += 0x7FFFu + ((u >> 16) & 1u);   // RNE
    return (unsigned short)(u >> 16);
}
// packed f32x2 -> bf16x2 (RNE), 1 instr for 2 elements
__device__ __forceinline__ unsigned cvtpk(float lo, float hi) {
    unsigned r;
    asm("v_cvt_pk_bf16_f32 %0, %1, %2" : "=v"(r) : "v"(lo), "v"(hi));
    return r;
}
__device__ __forceinline__ void ij_of(int p, int& i, int& j) {
    float s = sqrtf(8.0f * (float)p + 1.0f);
    i = (int)((s - 1.0f) * 0.5f);
    while ((i + 1) * (i + 2) / 2 <= p) ++i;
    while (i * (i + 1) / 2 > p) --i;
    j = p - i * (i + 1) / 2;
}
// h1 A-fragment: relu(unpack(u)+unpack(v)) packed to 8 bf16
__device__ __forceinline__ short8 buildA(uint4 uu, uint4 vv) {
    unsigned ua[4] = {uu.x, uu.y, uu.z, uu.w};
    unsigned va[4] = {vv.x, vv.y, vv.z, vv.w};
    union { unsigned u[4]; short8 s; } c;
    #pragma unroll
    for (int q = 0; q < 4; ++q) {
        float lo = asf(ua[q] << 16)         + asf(va[q] << 16);
        float hi = asf(ua[q] & 0xFFFF0000u) + asf(va[q] & 0xFFFF0000u);
        c.u[q] = cvtpk(fmaxf(lo, 0.f), fmaxf(hi, 0.f));
    }
    return c.s;
}
// same, returning raw uint4 (for LDS b128 store)
__device__ __forceinline__ uint4 build4(uint4 uu, uint4 vv) {
    union { uint4 v; short8 s; } c;
    c.s = buildA(uu, vv);
    return c.v;
}

// ---- fused preprocessing ------------------------------------------------
// grid (33, 8): x<32 -> U/V blocks; x==32 -> zero summed + transpose jobs
__global__ __launch_bounds__(256) void k_pre(
    const float* __restrict__ x, const float* __restrict__ code,
    const float* __restrict__ w1, const float* __restrict__ b1,
    const float* __restrict__ w2, const float* __restrict__ w3,
    unsigned short* __restrict__ ub, unsigned short* __restrict__ vb,
    unsigned short* __restrict__ w2t, unsigned short* __restrict__ w3t,
    float* __restrict__ summed)
{
    const int tid = threadIdx.x;
    if (blockIdx.x < 32) {
        const int ig = blockIdx.x, b = blockIdx.y, d = tid;
        float q = b1[d];
        const float* cp = code + b * 128;
        #pragma unroll 16
        for (int t = 0; t < 128; ++t) q += cp[t] * w1[(132 + t) * 256 + d];
        float su[8], sv[8];
        #pragma unroll
        for (int k = 0; k < 8; ++k) { su[k] = q; sv[k] = 0.f; }
        const float* xp = x + (b * 64) * 256 + ig * 8;
        #pragma unroll 8
        for (int c = 0; c < 64; ++c) {
            const float wu = w1[c * 256 + d];
            const float wv = w1[(66 + c) * 256 + d];
            const float* xc = xp + c * 256;          // uniform -> scalar loads
            #pragma unroll
            for (int k = 0; k < 8; ++k) { su[k] += xc[k] * wu; sv[k] += xc[k] * wv; }
        }
        const float wyu = w1[64 * 256 + d],  wxu = w1[65 * 256 + d];
        const float wyv = w1[130 * 256 + d], wxv = w1[131 * 256 + d];
        #pragma unroll
        for (int k = 0; k < 8; ++k) {
            const int i = ig * 8 + k;
            const float yy = (float)(i >> 4) * (2.0f / 15.0f) - 1.0f;
            const float xx = (float)(i & 15) * (2.0f / 15.0f) - 1.0f;
            ub[(b * 256 + i) * 256 + d] = f2bf(su[k] + yy * wyu + xx * wxu);
            vb[(b * 256 + i) * 256 + d] = f2bf(sv[k] + yy * wyv + xx * wxv);
        }
    } else {
        __shared__ float t[64][65];
        const int y = blockIdx.y;
        summed[y * 256 + tid] = 0.f;                 // re-zeroed every replay
        const int tx = tid & 63, ty = tid >> 6;
        for (int jj = 0; jj < 4; ++jj) {
            const int job = y * 4 + jj;              // 0..31
            const float* src = (job & 16) ? w3 : w2;
            unsigned short* dst = (job & 16) ? w3t : w2t;
            const int k0 = ((job >> 2) & 3) * 64, n0 = (job & 3) * 64;
            __syncthreads();
            #pragma unroll
            for (int r = ty; r < 64; r += 4) t[r][tx] = src[(k0 + r) * 256 + n0 + tx];
            __syncthreads();
            #pragma unroll
            for (int r = ty; r < 64; r += 4) dst[(n0 + r) * 256 + k0 + tx] = f2bf(t[tx][r]);
        }
    }
}

// ---- fused g_theta chain for 256 pairs (2Mx4N wave grid) ----------------
// Chunk swizzle: 16B chunk c of row r stored at chunk (c ^ (r&7)).
__global__ __launch_bounds__(512) void k_fuse(
    const unsigned short* __restrict__ ub, const unsigned short* __restrict__ vb,
    const unsigned short* __restrict__ w2t, const unsigned short* __restrict__ w3t,
    const float* __restrict__ b2, const float* __restrict__ b3,
    float* __restrict__ summed)
{
    extern __shared__ unsigned short lds[];        // [256][256] bf16 = 128KiB
    const int tid  = threadIdx.x;
    const int pt   = blockIdx.x, b = blockIdx.y;
    const int lane = tid & 63, w = tid >> 6;
    const int wm   = w >> 2, wn = w & 3;           // 2M x 4N wave grid
    const int lm   = lane & 15, quad = lane >> 4;

    // weight slice bases (lane lm -> n-row, quad -> k byte group)
    const unsigned short* bb2 = w2t + ((wn * 64 + lm) * 256) + quad * 8;
    const unsigned short* bb3 = w3t + ((wn * 64 + lm) * 256) + quad * 8;

    // hoist GEMM1 W2 frags ks=0,1 (latency hidden under the h1 build)
    short8 bbuf[2][4];   // [parity][nt]
    #pragma unroll
    for (int kk = 0; kk < 2; ++kk)
        #pragma unroll
        for (int nt = 0; nt < 4; ++nt)
            bbuf[kk][nt] = *(const short8*)(bb2 + nt * 4096 + kk * 32);

    // ---- build h1 = relu(U_i + V_j) into LDS (each elem built once) ----
    {
        const int r = tid >> 1, half = tid & 1;    // 2 threads/row
        const int p = pt * 256 + r;                // < 32768 always
        int i, j; ij_of(p, i, j);
        const unsigned short* up = ub + ((b * 256 + i) * 256) + half * 128;
        const unsigned short* vp = vb + ((b * 256 + j) * 256) + half * 128;
        const int rs = r & 7;
        #pragma unroll
        for (int it = 0; it < 16; ++it) {
            const uint4 uu = *(const uint4*)(up + it * 8);
            const uint4 vv = *(const uint4*)(vp + it * 8);
            const uint4 r4 = build4(uu, vv);
            const int chunk = half * 16 + it;
            *(uint4*)(&lds[r * 256 + ((chunk ^ rs) << 3)]) = r4;
        }
    }
    __syncthreads();

    const float4v zero4 = {0.f, 0.f, 0.f, 0.f};

    // ---- GEMM1 (SWAPPED): acc1[nt][mt] = h2^T; A = W2frag (L2, 2-deep),
    //      B = h1frag (LDS). Wave: rows wm*128..+127, cols wn*64..+63 ----
    float4v acc1[4][8];
    #pragma unroll
    for (int nt = 0; nt < 4; ++nt)
        #pragma unroll
        for (int mt = 0; mt < 8; ++mt) acc1[nt][mt] = zero4;
    {
        for (int ks = 0; ks < 8; ++ks) {
            const int pr = ks & 1;
            short8 bcur[4];
            #pragma unroll
            for (int nt = 0; nt < 4; ++nt) bcur[nt] = bbuf[pr][nt];
            if (ks < 6) {
                #pragma unroll
                for (int nt = 0; nt < 4; ++nt)
                    bbuf[pr][nt] = *(const short8*)(bb2 + nt * 4096 + (ks + 2) * 32);
            }
            const int coff = ((ks * 4 + quad) ^ (lm & 7)) << 3;
            __builtin_amdgcn_s_setprio(1);
            #pragma unroll
            for (int mt = 0; mt < 8; ++mt) {
                const short8 afr = *(const short8*)(
                    &lds[(wm * 128 + mt * 16 + lm) * 256 + coff]);
                #pragma unroll
                for (int nt = 0; nt < 4; ++nt)
                    acc1[nt][mt] = __builtin_amdgcn_mfma_f32_16x16x32_bf16(
                        bcur[nt], afr, acc1[nt][mt], 0, 0, 0);
            }
            __builtin_amdgcn_s_setprio(0);
        }
    }
    __syncthreads();   // all h1 reads done; tile reusable

    // hoist GEMM2 W3 frags ks=0,1 (latency hidden under the scatter)
    #pragma unroll
    for (int kk = 0; kk < 2; ++kk)
        #pragma unroll
        for (int nt = 0; nt < 4; ++nt)
            bbuf[kk][nt] = *(const short8*)(bb3 + nt * 4096 + kk * 32);

    // ---- scatter h2 = relu(acc1+b2): acc is h2^T (lane lm = pair,
    //      n = wn*64 + nt*16 + quad*4 + rg) -> 32 ds_write_b64/thread ----
    #pragma unroll
    for (int nt = 0; nt < 4; ++nt) {
        const float4 bbv = *(const float4*)(b2 + wn * 64 + nt * 16 + quad * 4);
        #pragma unroll
        for (int mt = 0; mt < 8; ++mt) {
            const int row = wm * 128 + mt * 16 + lm;   // pair
            const float v0 = fmaxf(acc1[nt][mt][0] + bbv.x, 0.f);
            const float v1 = fmaxf(acc1[nt][mt][1] + bbv.y, 0.f);
            const float v2 = fmaxf(acc1[nt][mt][2] + bbv.z, 0.f);
            const float v3 = fmaxf(acc1[nt][mt][3] + bbv.w, 0.f);
            uint2 pk; pk.x = cvtpk(v0, v1); pk.y = cvtpk(v2, v3);
            const int c0 = wn * 8 + nt * 2 + (quad >> 1);  // 16B chunk of n
            *(uint2*)(&lds[row * 256 +
                           (((c0 ^ (row & 7)) << 3) | ((quad & 1) << 2))]) = pk;
        }
    }
    __syncthreads();

    // ---- GEMM2 (normal): rel = h2 @ W3; A = h2frag (LDS), B = W3frag
    //      (L2, 2-deep). Wave: rows wm*128..+127, cols wn*64..+63 ----
    float4v acc2[8][4];
    #pragma unroll
    for (int mt = 0; mt < 8; ++mt)
        #pragma unroll
        for (int nt = 0; nt < 4; ++nt) acc2[mt][nt] = zero4;
    {
        for (int ks = 0; ks < 8; ++ks) {
            const int pr = ks & 1;
            short8 bcur[4];
            #pragma unroll
            for (int nt = 0; nt < 4; ++nt) bcur[nt] = bbuf[pr][nt];
            if (ks < 6) {
                #pragma unroll
                for (int nt = 0; nt < 4; ++nt)
                    bbuf[pr][nt] = *(const short8*)(bb3 + nt * 4096 + (ks + 2) * 32);
            }
            const int coff = ((ks * 4 + quad) ^ (lm & 7)) << 3;
            __builtin_amdgcn_s_setprio(1);
            #pragma unroll
            for (int mt = 0; mt < 8; ++mt) {
                const short8 a = *(const short8*)(
                    &lds[(wm * 128 + mt * 16 + lm) * 256 + coff]);
                #pragma unroll
                for (int nt = 0; nt < 4; ++nt)
                    acc2[mt][nt] = __builtin_amdgcn_mfma_f32_16x16x32_bf16(
                        a, bcur[nt], acc2[mt][nt], 0, 0, 0);
            }
            __builtin_amdgcn_s_setprio(0);
        }
    }

    // ---- relu + column-sum over this wave's 128 pairs -> atomicAdd ------
    #pragma unroll
    for (int nt = 0; nt < 4; ++nt) {
        const int col = wn * 64 + nt * 16 + lm;
        const float bb = b3[col];
        float s = 0.f;
        #pragma unroll
        for (int mt = 0; mt < 8; ++mt)
            #pragma unroll
            for (int rg = 0; rg < 4; ++rg)
                s += fmaxf(acc2[mt][nt][rg] + bb, 0.f);
        s += __shfl_xor(s, 16);
        s += __shfl_xor(s, 32);
        if (quad == 0)
            atomicAdd(&summed[b * 256 + col], s);
    }
}

// ---- leftover 128 pairs (g_theta) + f_phi -------------------------------
// 8 blocks (one per b) x 1024 threads; waves 0-7 run the GEMM chain for
// pairs 32768..32895, adds into summed[b] locally, then f_phi.
__global__ __launch_bounds__(1024) void k_tail(
    const unsigned short* __restrict__ ub, const unsigned short* __restrict__ vb,
    const unsigned short* __restrict__ w2t, const unsigned short* __restrict__ w3t,
    const float* __restrict__ b2, const float* __restrict__ b3,
    const float* __restrict__ summed,
    const float* __restrict__ fw1, const float* __restrict__ fb1,
    const float* __restrict__ fw2, const float* __restrict__ fb2,
    const float* __restrict__ fw3, const float* __restrict__ fb3,
    float* __restrict__ out)
{
    extern __shared__ unsigned short lds[];        // 128KiB tile + 7KiB f32
    float* ext = (float*)(lds + 65536);            // [256]
    float* s0  = ext + 256;                        // [256]
    float* s1  = s0 + 256;                         // [256]
    float* red = s1 + 256;                         // [1024]
    const int b = blockIdx.x, tid = threadIdx.x;
    const int lane = tid & 63, w = tid >> 6;
    const int lm = lane & 15, quad = lane >> 4;
    const float4v zero4 = {0.f, 0.f, 0.f, 0.f};

    // stage W2^T swizzled (all 1024 threads)
    #pragma unroll
    for (int it = 0; it < 8; ++it) {
        const int idx = it * 1024 + tid;
        const int n = idx >> 5, c = idx & 31;
        const uint4 d4 = *(const uint4*)(w2t + n * 256 + c * 8);
        *(uint4*)(&lds[n * 256 + ((c ^ (n & 7)) << 3)]) = d4;
    }
    // pair setup (waves 0-7 own 16 pairs each; clamp for idle waves)
    const int pp = 32768 + w * 16 + lm;
    const int p  = pp < NPAIR ? pp : NPAIR - 1;
    int i, j; ij_of(p, i, j);
    const unsigned short* up = ub + ((b * 256 + i) * 256) + quad * 8;
    const unsigned short* vp = vb + ((b * 256 + j) * 256) + quad * 8;
    __syncthreads();

    // GEMM1 (swapped): acc1[nt] = h2^T for this wave's 16 pairs
    float4v acc1[16];
    #pragma unroll
    for (int nt = 0; nt < 16; ++nt) acc1[nt] = zero4;
    if (tid < 512) {
        #pragma unroll
        for (int ks = 0; ks < 8; ++ks) {
            const uint4 cu = *(const uint4*)(up + ks * 32);
            const uint4 cv = *(const uint4*)(vp + ks * 32);
            const short8 afr = buildA(cu, cv);
            const int coff = ((ks * 4 + quad) ^ (lm & 7)) << 3;
            #pragma unroll
            for (int nt = 0; nt < 16; ++nt) {
                const short8 bfr = *(const short8*)(&lds[(nt * 16 + lm) * 256 + coff]);
                acc1[nt] = __builtin_amdgcn_mfma_f32_16x16x32_bf16(
                    bfr, afr, acc1[nt], 0, 0, 0);
            }
        }
    }
    __syncthreads();   // GEMM1 LDS reads done; tile reusable

    if (tid < 512) {   // scatter h2 rows 0..127 (swizzled, same encoding)
        #pragma unroll
        for (int nt = 0; nt < 16; ++nt) {
            const float4 bbv = *(const float4*)(b2 + nt * 16 + quad * 4);
            const int row = w * 16 + lm;               // pair row 0..127
            const float v0 = fmaxf(acc1[nt][0] + bbv.x, 0.f);
            const float v1 = fmaxf(acc1[nt][1] + bbv.y, 0.f);
            const float v2 = fmaxf(acc1[nt][2] + bbv.z, 0.f);
            const float v3 = fmaxf(acc1[nt][3] + bbv.w, 0.f);
            uint2 pk; pk.x = cvtpk(v0, v1); pk.y = cvtpk(v2, v3);
            const int c0 = nt * 2 + (quad >> 1);
            *(uint2*)(&lds[row * 256 + (((c0 ^ (row & 7)) << 3) | ((quad & 1) << 2))]) = pk;
        }
    }
    __syncthreads();

    // GEMM2: N-split, wave w cols w*32..+31, rows 0..127
    float4v acc2[8][2];
    #pragma unroll
    for (int mt = 0; mt < 8; ++mt)
        #pragma unroll
        for (int nt = 0; nt < 2; ++nt) acc2[mt][nt] = zero4;
    if (tid < 512) {
        const unsigned short* bb3 = w3t + ((w * 32 + lm) * 256) + quad * 8;
        #pragma unroll
        for (int ks = 0; ks < 8; ++ks) {
            short8 bcur[2];
            #pragma unroll
            for (int nt = 0; nt < 2; ++nt)
                bcur[nt] = *(const short8*)(bb3 + nt * 4096 + ks * 32);
            #pragma unroll
            for (int mt = 0; mt < 8; ++mt) {
                const int row = mt * 16 + lm;
                const short8 a = *(const short8*)(
                    &lds[row * 256 + (((ks * 4 + quad) ^ (row & 7)) << 3)]);
                #pragma unroll
                for (int nt = 0; nt < 2; ++nt)
                    acc2[mt][nt] = __builtin_amdgcn_mfma_f32_16x16x32_bf16(
                        a, bcur[nt], acc2[mt][nt], 0, 0, 0);
            }
        }
        #pragma unroll
        for (int nt = 0; nt < 2; ++nt) {
            const int col = w * 32 + nt * 16 + lm;
            const float bb = b3[col];
            float s = 0.f;
            #pragma unroll
            for (int mt = 0; mt < 8; ++mt)
                #pragma unroll
                for (int rg = 0; rg < 4; ++rg)
                    s += fmaxf(acc2[mt][nt][rg] + bb, 0.f);
            s += __shfl_xor(s, 16);
            s += __shfl_xor(s, 32);
            if (quad == 0) ext[col] = s;
        }
    }
    __syncthreads();

    // ---- f_phi (fp32), 4-way k-split per 256-wide layer ----
    const int d = tid & 255, kh = tid >> 8;     // kh 0..3
    if (tid < 256) s0[tid] = summed[b * 256 + tid] + ext[tid];
    __syncthreads();
    float pk = 0.f;
    #pragma unroll 16
    for (int k = kh * 64; k < kh * 64 + 64; ++k) pk += s0[k] * fw1[k * 256 + d];
    red[kh * 256 + d] = pk;
    __syncthreads();
    if (tid < 256)
        s1[tid] = fmaxf(red[tid] + red[256 + tid] + red[512 + tid] + red[768 + tid]
                        + fb1[tid], 0.f);
    __syncthreads();
    pk = 0.f;
    #pragma unroll 16
    for (int k = kh * 64; k < kh * 64 + 64; ++k) pk += s1[k] * fw2[k * 256 + d];
    red[kh * 256 + d] = pk;
    __syncthreads();
    if (tid < 256)
        s0[tid] = fmaxf(red[tid] + red[256 + tid] + red[512 + tid] + red[768 + tid]
                        + fb2[tid], 0.f);
    __syncthreads();
    const int d3 = tid & 31, kh3 = tid >> 5;    // kh3 0..31
    pk = 0.f;
    #pragma unroll
    for (int k = kh3 * 8; k < kh3 * 8 + 8; ++k) pk += s0[k] * fw3[k * 32 + d3];
    red[kh3 * 32 + d3] = pk;
    __syncthreads();
    if (tid < 32) {
        float o = fb3[tid];
        #pragma unroll 8
        for (int r = 0; r < 32; ++r) o += red[r * 32 + tid];
        out[b * 32 + tid] = o;
    }
}

extern "C" void kernel_launch(void* const* d_in, const int* in_sizes, int n_in,
                              void* d_out, int out_size, void* d_ws, size_t ws_size,
                              hipStream_t stream) {
    const float* x    = (const float*)d_in[0];
    const float* code = (const float*)d_in[1];
    const float* gw1  = (const float*)d_in[2];
    const float* gb1  = (const float*)d_in[3];
    const float* gw2  = (const float*)d_in[4];
    const float* gb2  = (const float*)d_in[5];
    const float* gw3  = (const float*)d_in[6];
    const float* gb3  = (const float*)d_in[7];
    const float* fw1  = (const float*)d_in[8];
    const float* fb1  = (const float*)d_in[9];
    const float* fw2  = (const float*)d_in[10];
    const float* fb2  = (const float*)d_in[11];
    const float* fw3  = (const float*)d_in[12];
    const float* fb3  = (const float*)d_in[13];
    float* out = (float*)d_out;

    // workspace layout (bytes), total ~2.27 MB
    char* ws = (char*)d_ws;
    unsigned short* ub  = (unsigned short*)(ws);               // 1 MiB
    unsigned short* vb  = (unsigned short*)(ws + 1048576);     // 1 MiB
    unsigned short* w2t = (unsigned short*)(ws + 2097152);     // 128 KiB
    unsigned short* w3t = (unsigned short*)(ws + 2228224);     // 128 KiB
    float* summed = (float*)(ws + 2359296);                    // 8 KiB

    hipLaunchKernelGGL(k_pre, dim3(33, 8), dim3(256), 0, stream,
                       x, code, gw1, gb1, gw2, gw3, ub, vb, w2t, w3t, summed);
    hipLaunchKernelGGL(k_fuse, dim3(128, 8), dim3(512), 131072, stream,
                       ub, vb, w2t, w3t, gb2, gb3, summed);
    hipLaunchKernelGGL(k_tail, dim3(8), dim3(1024), 138240, stream,
                       ub, vb, w2t, w3t, gb2, gb3, summed,
                       fw1, fb1, fw2, fb2, fw3, fb3, out);
}

// Round 13
// 211.904 us; speedup vs baseline: 1.0459x; 1.0459x over previous
//
#include <hip/hip_runtime.h>
#include <stdint.h>

// RelationalNetwork: B=8, C=64, O=256, TE=128, GT=FP=256, A=32
// v14 = v11 (84.9us proven) with GEMM2 re-geometried 2Mx4N + 4-deep W3:
//   k_pre : W2/W3 transpose->bf16, summed:=0, U/V precompute (pipelined)
//   k_fuse: grid (128,8) = 1024 uniform blocks. W2^T staged in LDS once;
//           GEMM1 M-split swapped mfma(W2,h1), in-reg h1 (3-deep U/V),
//           b64 h2^T scatter (all v11-proven). GEMM2 2Mx4N wave grid:
//           A (h2, LDS) 8 reads/ks reused x4, W3^T from L2 4-deep.
//           colsum -> atomicAdd summed.
//   k_tail: 8 blocks x 1024 thr; leftover 128 pairs + f_phi (unchanged).

#define NPAIR 32896   // k_fuse covers 32768, k_tail the last 128

using short8  = __attribute__((ext_vector_type(8))) short;
using float4v = __attribute__((ext_vector_type(4))) float;

__device__ __forceinline__ float asf(unsigned u) {
    union { unsigned u; float f; } c; c.u = u; return c.f;
}
__device__ __forceinline__ unsigned short f2bf(float f) {
    union { float f; unsigned u; } c; c.f = f;
    unsigned u = c.u;
    u += 0x7FFFu + ((u >> 16) & 1u);   // RNE
    return (unsigned short)(u >> 16);
}
// packed f32x2 -> bf16x2 (RNE), 1 instr for 2 elements
__device__ __forceinline__ unsigned cvtpk(float lo, float hi) {
    unsigned r;
    asm("v_cvt_pk_bf16_f32 %0, %1, %2" : "=v"(r) : "v"(lo), "v"(hi));
    return r;
}
__device__ __forceinline__ void ij_of(int p, int& i, int& j) {
    float s = sqrtf(8.0f * (float)p + 1.0f);
    i = (int)((s - 1.0f) * 0.5f);
    while ((i + 1) * (i + 2) / 2 <= p) ++i;
    while (i * (i + 1) / 2 > p) --i;
    j = p - i * (i + 1) / 2;
}
// h1 A-fragment: relu(unpack(u)+unpack(v)) packed to 8 bf16
__device__ __forceinline__ short8 buildA(uint4 uu, uint4 vv) {
    unsigned ua[4] = {uu.x, uu.y, uu.z, uu.w};
    unsigned va[4] = {vv.x, vv.y, vv.z, vv.w};
    union { unsigned u[4]; short8 s; } c;
    #pragma unroll
    for (int q = 0; q < 4; ++q) {
        float lo = asf(ua[q] << 16)         + asf(va[q] << 16);
        float hi = asf(ua[q] & 0xFFFF0000u) + asf(va[q] & 0xFFFF0000u);
        c.u[q] = cvtpk(fmaxf(lo, 0.f), fmaxf(hi, 0.f));
    }
    return c.s;
}

// ---- fused preprocessing ------------------------------------------------
// grid (33, 8): x<32 -> U/V blocks; x==32 -> zero summed + transpose jobs
__global__ __launch_bounds__(256) void k_pre(
    const float* __restrict__ x, const float* __restrict__ code,
    const float* __restrict__ w1, const float* __restrict__ b1,
    const float* __restrict__ w2, const float* __restrict__ w3,
    unsigned short* __restrict__ ub, unsigned short* __restrict__ vb,
    unsigned short* __restrict__ w2t, unsigned short* __restrict__ w3t,
    float* __restrict__ summed)
{
    const int tid = threadIdx.x;
    if (blockIdx.x < 32) {
        const int ig = blockIdx.x, b = blockIdx.y, d = tid;
        float q = b1[d];
        const float* cp = code + b * 128;
        #pragma unroll 16
        for (int t = 0; t < 128; ++t) q += cp[t] * w1[(132 + t) * 256 + d];
        float su[8], sv[8];
        #pragma unroll
        for (int k = 0; k < 8; ++k) { su[k] = q; sv[k] = 0.f; }
        const float* xp = x + (b * 64) * 256 + ig * 8;
        #pragma unroll 8
        for (int c = 0; c < 64; ++c) {
            const float wu = w1[c * 256 + d];
            const float wv = w1[(66 + c) * 256 + d];
            const float* xc = xp + c * 256;          // uniform -> scalar loads
            #pragma unroll
            for (int k = 0; k < 8; ++k) { su[k] += xc[k] * wu; sv[k] += xc[k] * wv; }
        }
        const float wyu = w1[64 * 256 + d],  wxu = w1[65 * 256 + d];
        const float wyv = w1[130 * 256 + d], wxv = w1[131 * 256 + d];
        #pragma unroll
        for (int k = 0; k < 8; ++k) {
            const int i = ig * 8 + k;
            const float yy = (float)(i >> 4) * (2.0f / 15.0f) - 1.0f;
            const float xx = (float)(i & 15) * (2.0f / 15.0f) - 1.0f;
            ub[(b * 256 + i) * 256 + d] = f2bf(su[k] + yy * wyu + xx * wxu);
            vb[(b * 256 + i) * 256 + d] = f2bf(sv[k] + yy * wyv + xx * wxv);
        }
    } else {
        __shared__ float t[64][65];
        const int y = blockIdx.y;
        summed[y * 256 + tid] = 0.f;                 // re-zeroed every replay
        const int tx = tid & 63, ty = tid >> 6;
        for (int jj = 0; jj < 4; ++jj) {
            const int job = y * 4 + jj;              // 0..31
            const float* src = (job & 16) ? w3 : w2;
            unsigned short* dst = (job & 16) ? w3t : w2t;
            const int k0 = ((job >> 2) & 3) * 64, n0 = (job & 3) * 64;
            __syncthreads();
            #pragma unroll
            for (int r = ty; r < 64; r += 4) t[r][tx] = src[(k0 + r) * 256 + n0 + tx];
            __syncthreads();
            #pragma unroll
            for (int r = ty; r < 64; r += 4) dst[(n0 + r) * 256 + k0 + tx] = f2bf(t[tx][r]);
        }
    }
}

// ---- fused g_theta chain for 256 pairs (uniform full tiles) -------------
// Chunk swizzle everywhere: 16B chunk c of row r stored at chunk (c ^ (r&7)).
__global__ __launch_bounds__(512) void k_fuse(
    const unsigned short* __restrict__ ub, const unsigned short* __restrict__ vb,
    const unsigned short* __restrict__ w2t, const unsigned short* __restrict__ w3t,
    const float* __restrict__ b2, const float* __restrict__ b3,
    float* __restrict__ summed)
{
    extern __shared__ unsigned short lds[];        // 128 KiB
    const int tid  = threadIdx.x;
    const int pt   = blockIdx.x, b = blockIdx.y;
    const int lane = tid & 63, w = tid >> 6;
    const int lm   = lane & 15, quad = lane >> 4;

    // ---- stage W2^T[n][k] into LDS, chunk-swizzled ----
    #pragma unroll
    for (int it = 0; it < 16; ++it) {
        const int idx = it * 512 + tid;
        const int n = idx >> 5, c = idx & 31;
        const uint4 d = *(const uint4*)(w2t + n * 256 + c * 8);
        *(uint4*)(&lds[n * 256 + ((c ^ (n & 7)) << 3)]) = d;
    }

    // ---- GEMM1 row setup (wave owns rows w*32..w*32+31; always valid) ----
    const unsigned short* up[2];
    const unsigned short* vp[2];
    #pragma unroll
    for (int mt = 0; mt < 2; ++mt) {
        const int p = pt * 256 + w * 32 + mt * 16 + lm;   // < 32768 always
        int i, j; ij_of(p, i, j);
        up[mt] = ub + ((b * 256 + i) * 256) + quad * 8;
        vp[mt] = vb + ((b * 256 + j) * 256) + quad * 8;
    }
    __syncthreads();

    const float4v zero4 = {0.f, 0.f, 0.f, 0.f};

    // ---- GEMM1 (SWAPPED): acc1[nt][mt] = h2^T; A = W2frag (LDS),
    //      B = h1frag built in-reg from U/V (3-deep prefetch) ----
    float4v acc1[16][2];
    #pragma unroll
    for (int nt = 0; nt < 16; ++nt)
        #pragma unroll
        for (int mt = 0; mt < 2; ++mt) acc1[nt][mt] = zero4;
    {
        uint4 cu[3][2], cv[3][2];    // [slot][mt]
        #pragma unroll
        for (int kk = 0; kk < 3; ++kk)
            #pragma unroll
            for (int mt = 0; mt < 2; ++mt) {
                cu[kk][mt] = *(const uint4*)(up[mt] + kk * 32);
                cv[kk][mt] = *(const uint4*)(vp[mt] + kk * 32);
            }
        #pragma unroll
        for (int ks = 0; ks < 8; ++ks) {
            const int pr = ks % 3;
            short8 afr[2];
            #pragma unroll
            for (int mt = 0; mt < 2; ++mt) afr[mt] = buildA(cu[pr][mt], cv[pr][mt]);
            if (ks < 5) {
                #pragma unroll
                for (int mt = 0; mt < 2; ++mt) {
                    cu[pr][mt] = *(const uint4*)(up[mt] + (ks + 3) * 32);
                    cv[pr][mt] = *(const uint4*)(vp[mt] + (ks + 3) * 32);
                }
            }
            const int coff = ((ks * 4 + quad) ^ (lm & 7)) << 3;
            __builtin_amdgcn_s_setprio(1);
            #pragma unroll
            for (int ng = 0; ng < 4; ++ng) {
                short8 bfr[4];
                #pragma unroll
                for (int q = 0; q < 4; ++q)
                    bfr[q] = *(const short8*)(&lds[((ng * 4 + q) * 16 + lm) * 256 + coff]);
                #pragma unroll
                for (int q = 0; q < 4; ++q)
                    #pragma unroll
                    for (int mt = 0; mt < 2; ++mt)
                        acc1[ng * 4 + q][mt] = __builtin_amdgcn_mfma_f32_16x16x32_bf16(
                            bfr[q], afr[mt], acc1[ng * 4 + q][mt], 0, 0, 0);
            }
            __builtin_amdgcn_s_setprio(0);
        }
    }
    __syncthreads();   // all waves done reading W2 region

    // ---- hoist GEMM2 W3 frags ks=0..3 (4-deep; hidden under scatter) ----
    const int wm = w >> 2, wn = w & 3;             // GEMM2: 2M x 4N wave grid
    const unsigned short* bb3 = w3t + ((wn * 64 + lm) * 256) + quad * 8;
    short8 b3buf[4][4];   // [slot][nt]
    #pragma unroll
    for (int kk = 0; kk < 4; ++kk)
        #pragma unroll
        for (int nt = 0; nt < 4; ++nt)
            b3buf[kk][nt] = *(const short8*)(bb3 + nt * 4096 + kk * 32);

    // ---- scatter h2 = relu(acc1+b2): acc is h2^T (lane lm = pair,
    //      n = nt*16 + quad*4 + rg) -> 32 ds_write_b64/thread ----
    #pragma unroll
    for (int nt = 0; nt < 16; ++nt) {
        const float4 bbv = *(const float4*)(b2 + nt * 16 + quad * 4);
        #pragma unroll
        for (int mt = 0; mt < 2; ++mt) {
            const int row = w * 32 + mt * 16 + lm;     // pair
            const float v0 = fmaxf(acc1[nt][mt][0] + bbv.x, 0.f);
            const float v1 = fmaxf(acc1[nt][mt][1] + bbv.y, 0.f);
            const float v2 = fmaxf(acc1[nt][mt][2] + bbv.z, 0.f);
            const float v3 = fmaxf(acc1[nt][mt][3] + bbv.w, 0.f);
            uint2 pk; pk.x = cvtpk(v0, v1); pk.y = cvtpk(v2, v3);
            const int c0 = nt * 2 + (quad >> 1);       // 16B chunk of n
            *(uint2*)(&lds[row * 256 + (((c0 ^ (row & 7)) << 3) | ((quad & 1) << 2))]) = pk;
        }
    }
    __syncthreads();

    // ---- GEMM2: rel = h2 @ W3, 2Mx4N (wave: rows wm*128..+127, cols
    //      wn*64..+63); A from LDS (8 reads/ks, reused x4), B = W3^T from
    //      L2 (4-deep prefetch) ----
    float4v acc2[8][4];
    #pragma unroll
    for (int mt = 0; mt < 8; ++mt)
        #pragma unroll
        for (int nt = 0; nt < 4; ++nt) acc2[mt][nt] = zero4;
    {
        #pragma unroll
        for (int ks = 0; ks < 8; ++ks) {
            const int pr = ks & 3;
            short8 bcur[4];
            #pragma unroll
            for (int nt = 0; nt < 4; ++nt) bcur[nt] = b3buf[pr][nt];
            if (ks < 4) {
                #pragma unroll
                for (int nt = 0; nt < 4; ++nt)
                    b3buf[pr][nt] = *(const short8*)(bb3 + nt * 4096 + (ks + 4) * 32);
            }
            const int coff = ((ks * 4 + quad) ^ (lm & 7)) << 3;
            __builtin_amdgcn_s_setprio(1);
            #pragma unroll
            for (int mt = 0; mt < 8; ++mt) {
                const int row = wm * 128 + mt * 16 + lm;
                const short8 a = *(const short8*)(&lds[row * 256 + coff]);
                #pragma unroll
                for (int nt = 0; nt < 4; ++nt)
                    acc2[mt][nt] = __builtin_amdgcn_mfma_f32_16x16x32_bf16(
                        a, bcur[nt], acc2[mt][nt], 0, 0, 0);
            }
            __builtin_amdgcn_s_setprio(0);
        }
    }

    // ---- relu + column-sum over this wave's 128 pairs -> atomicAdd ------
    #pragma unroll
    for (int nt = 0; nt < 4; ++nt) {
        const int col = wn * 64 + nt * 16 + lm;
        const float bb = b3[col];
        float s = 0.f;
        #pragma unroll
        for (int mt = 0; mt < 8; ++mt)
            #pragma unroll
            for (int rg = 0; rg < 4; ++rg)
                s += fmaxf(acc2[mt][nt][rg] + bb, 0.f);
        s += __shfl_xor(s, 16);
        s += __shfl_xor(s, 32);
        if (quad == 0)
            atomicAdd(&summed[b * 256 + col], s);
    }
}

// ---- leftover 128 pairs (g_theta) + f_phi -------------------------------
// 8 blocks (one per b) x 1024 threads; waves 0-7 run the GEMM chain for
// pairs 32768..32895, adds into summed[b] locally, then f_phi.
__global__ __launch_bounds__(1024) void k_tail(
    const unsigned short* __restrict__ ub, const unsigned short* __restrict__ vb,
    const unsigned short* __restrict__ w2t, const unsigned short* __restrict__ w3t,
    const float* __restrict__ b2, const float* __restrict__ b3,
    const float* __restrict__ summed,
    const float* __restrict__ fw1, const float* __restrict__ fb1,
    const float* __restrict__ fw2, const float* __restrict__ fb2,
    const float* __restrict__ fw3, const float* __restrict__ fb3,
    float* __restrict__ out)
{
    extern __shared__ unsigned short lds[];        // 128KiB tile + 7KiB f32
    float* ext = (float*)(lds + 65536);            // [256]
    float* s0  = ext + 256;                        // [256]
    float* s1  = s0 + 256;                         // [256]
    float* red = s1 + 256;                         // [1024]
    const int b = blockIdx.x, tid = threadIdx.x;
    const int lane = tid & 63, w = tid >> 6;
    const int lm = tid & 15, quad = lane >> 4;
    const float4v zero4 = {0.f, 0.f, 0.f, 0.f};

    // stage W2^T swizzled (all 1024 threads)
    #pragma unroll
    for (int it = 0; it < 8; ++it) {
        const int idx = it * 1024 + tid;
        const int n = idx >> 5, c = idx & 31;
        const uint4 d4 = *(const uint4*)(w2t + n * 256 + c * 8);
        *(uint4*)(&lds[n * 256 + ((c ^ (n & 7)) << 3)]) = d4;
    }
    // pair setup (waves 0-7 own 16 pairs each; clamp for idle waves)
    const int pp = 32768 + w * 16 + lm;
    const int p  = pp < NPAIR ? pp : NPAIR - 1;
    int i, j; ij_of(p, i, j);
    const unsigned short* up = ub + ((b * 256 + i) * 256) + quad * 8;
    const unsigned short* vp = vb + ((b * 256 + j) * 256) + quad * 8;
    __syncthreads();

    // GEMM1 (swapped): acc1[nt] = h2^T for this wave's 16 pairs
    float4v acc1[16];
    #pragma unroll
    for (int nt = 0; nt < 16; ++nt) acc1[nt] = zero4;
    if (tid < 512) {
        #pragma unroll
        for (int ks = 0; ks < 8; ++ks) {
            const uint4 cu = *(const uint4*)(up + ks * 32);
            const uint4 cv = *(const uint4*)(vp + ks * 32);
            const short8 afr = buildA(cu, cv);
            const int coff = ((ks * 4 + quad) ^ (lm & 7)) << 3;
            #pragma unroll
            for (int nt = 0; nt < 16; ++nt) {
                const short8 bfr = *(const short8*)(&lds[(nt * 16 + lm) * 256 + coff]);
                acc1[nt] = __builtin_amdgcn_mfma_f32_16x16x32_bf16(
                    bfr, afr, acc1[nt], 0, 0, 0);
            }
        }
    }
    __syncthreads();   // GEMM1 LDS reads done; tile reusable

    if (tid < 512) {   // scatter h2 rows 0..127 (swizzled, same encoding)
        #pragma unroll
        for (int nt = 0; nt < 16; ++nt) {
            const float4 bbv = *(const float4*)(b2 + nt * 16 + quad * 4);
            const int row = w * 16 + lm;               // pair row 0..127
            const float v0 = fmaxf(acc1[nt][0] + bbv.x, 0.f);
            const float v1 = fmaxf(acc1[nt][1] + bbv.y, 0.f);
            const float v2 = fmaxf(acc1[nt][2] + bbv.z, 0.f);
            const float v3 = fmaxf(acc1[nt][3] + bbv.w, 0.f);
            uint2 pk; pk.x = cvtpk(v0, v1); pk.y = cvtpk(v2, v3);
            const int c0 = nt * 2 + (quad >> 1);
            *(uint2*)(&lds[row * 256 + (((c0 ^ (row & 7)) << 3) | ((quad & 1) << 2))]) = pk;
        }
    }
    __syncthreads();

    // GEMM2: N-split, wave w cols w*32..+31, rows 0..127
    float4v acc2[8][2];
    #pragma unroll
    for (int mt = 0; mt < 8; ++mt)
        #pragma unroll
        for (int nt = 0; nt < 2; ++nt) acc2[mt][nt] = zero4;
    if (tid < 512) {
        const unsigned short* bb3 = w3t + ((w * 32 + lm) * 256) + quad * 8;
        #pragma unroll
        for (int ks = 0; ks < 8; ++ks) {
            short8 bcur[2];
            #pragma unroll
            for (int nt = 0; nt < 2; ++nt)
                bcur[nt] = *(const short8*)(bb3 + nt * 4096 + ks * 32);
            #pragma unroll
            for (int mt = 0; mt < 8; ++mt) {
                const int row = mt * 16 + lm;
                const short8 a = *(const short8*)(
                    &lds[row * 256 + (((ks * 4 + quad) ^ (row & 7)) << 3)]);
                #pragma unroll
                for (int nt = 0; nt < 2; ++nt)
                    acc2[mt][nt] = __builtin_amdgcn_mfma_f32_16x16x32_bf16(
                        a, bcur[nt], acc2[mt][nt], 0, 0, 0);
            }
        }
        #pragma unroll
        for (int nt = 0; nt < 2; ++nt) {
            const int col = w * 32 + nt * 16 + lm;
            const float bb = b3[col];
            float s = 0.f;
            #pragma unroll
            for (int mt = 0; mt < 8; ++mt)
                #pragma unroll
                for (int rg = 0; rg < 4; ++rg)
                    s += fmaxf(acc2[mt][nt][rg] + bb, 0.f);
            s += __shfl_xor(s, 16);
            s += __shfl_xor(s, 32);
            if (quad == 0) ext[col] = s;
        }
    }
    __syncthreads();

    // ---- f_phi (fp32), 4-way k-split per 256-wide layer ----
    const int d = tid & 255, kh = tid >> 8;     // kh 0..3
    if (tid < 256) s0[tid] = summed[b * 256 + tid] + ext[tid];
    __syncthreads();
    float pk = 0.f;
    #pragma unroll 16
    for (int k = kh * 64; k < kh * 64 + 64; ++k) pk += s0[k] * fw1[k * 256 + d];
    red[kh * 256 + d] = pk;
    __syncthreads();
    if (tid < 256)
        s1[tid] = fmaxf(red[tid] + red[256 + tid] + red[512 + tid] + red[768 + tid]
                        + fb1[tid], 0.f);
    __syncthreads();
    pk = 0.f;
    #pragma unroll 16
    for (int k = kh * 64; k < kh * 64 + 64; ++k) pk += s1[k] * fw2[k * 256 + d];
    red[kh * 256 + d] = pk;
    __syncthreads();
    if (tid < 256)
        s0[tid] = fmaxf(red[tid] + red[256 + tid] + red[512 + tid] + red[768 + tid]
                        + fb2[tid], 0.f);
    __syncthreads();
    const int d3 = tid & 31, kh3 = tid >> 5;    // kh3 0..31
    pk = 0.f;
    #pragma unroll
    for (int k = kh3 * 8; k < kh3 * 8 + 8; ++k) pk += s0[k] * fw3[k * 32 + d3];
    red[kh3 * 32 + d3] = pk;
    __syncthreads();
    if (tid < 32) {
        float o = fb3[tid];
        #pragma unroll 8
        for (int r = 0; r < 32; ++r) o += red[r * 32 + tid];
        out[b * 32 + tid] = o;
    }
}

extern "C" void kernel_launch(void* const* d_in, const int* in_sizes, int n_in,
                              void* d_out, int out_size, void* d_ws, size_t ws_size,
                              hipStream_t stream) {
    const float* x    = (const float*)d_in[0];
    const float* code = (const float*)d_in[1];
    const float* gw1  = (const float*)d_in[2];
    const float* gb1  = (const float*)d_in[3];
    const float* gw2  = (const float*)d_in[4];
    const float* gb2  = (const float*)d_in[5];
    const float* gw3  = (const float*)d_in[6];
    const float* gb3  = (const float*)d_in[7];
    const float* fw1  = (const float*)d_in[8];
    const float* fb1  = (const float*)d_in[9];
    const float* fw2  = (const float*)d_in[10];
    const float* fb2  = (const float*)d_in[11];
    const float* fw3  = (const float*)d_in[12];
    const float* fb3  = (const float*)d_in[13];
    float* out = (float*)d_out;

    // workspace layout (bytes), total ~2.27 MB
    char* ws = (char*)d_ws;
    unsigned short* ub  = (unsigned short*)(ws);               // 1 MiB
    unsigned short* vb  = (unsigned short*)(ws + 1048576);     // 1 MiB
    unsigned short* w2t = (unsigned short*)(ws + 2097152);     // 128 KiB
    unsigned short* w3t = (unsigned short*)(ws + 2228224);     // 128 KiB
    float* summed = (float*)(ws + 2359296);                    // 8 KiB

    hipLaunchKernelGGL(k_pre, dim3(33, 8), dim3(256), 0, stream,
                       x, code, gw1, gb1, gw2, gw3, ub, vb, w2t, w3t, summed);
    hipLaunchKernelGGL(k_fuse, dim3(128, 8), dim3(512), 131072, stream,
                       ub, vb, w2t, w3t, gb2, gb3, summed);
    hipLaunchKernelGGL(k_tail, dim3(8), dim3(1024), 138240, stream,
                       ub, vb, w2t, w3t, gb2, gb3, summed,
                       fw1, fb1, fw2, fb2, fw3, fb3, out);
}

// Round 14
// 205.395 us; speedup vs baseline: 1.0791x; 1.0317x over previous
//
#include <hip/hip_runtime.h>
#include <stdint.h>

// RelationalNetwork: B=8, C=64, O=256, TE=128, GT=FP=256, A=32
// v15 = v11 k_fuse (84.9us, best) verbatim + dieted k_tail:
//   k_pre : W2/W3 transpose->bf16, summed:=0, U/V precompute (pipelined)
//   k_fuse: grid (128,8) = 1024 uniform blocks (exactly 4 rounds). W2^T in
//           LDS once; GEMM1 M-split swapped mfma(W2,h1), in-reg h1 (3-deep
//           U/V), b64 h2^T scatter; GEMM2 N-split, W3^T from L2 2-deep;
//           colsum -> atomicAdd summed.  [v11-proven, unchanged]
//   k_tail: leftover 128 pairs with 4pgx4cg wave grid (wave = 32 pairs x
//           64 cols): h1 built once in LDS, W2/W3 64-col slices from L2
//           (2-deep, 16-wave TLP), no W2 staging; then f_phi.

#define NPAIR 32896   // k_fuse covers 32768, k_tail the last 128

using short8  = __attribute__((ext_vector_type(8))) short;
using float4v = __attribute__((ext_vector_type(4))) float;

__device__ __forceinline__ float asf(unsigned u) {
    union { unsigned u; float f; } c; c.u = u; return c.f;
}
__device__ __forceinline__ unsigned short f2bf(float f) {
    union { float f; unsigned u; } c; c.f = f;
    unsigned u = c.u;
    u += 0x7FFFu + ((u >> 16) & 1u);   // RNE
    return (unsigned short)(u >> 16);
}
// packed f32x2 -> bf16x2 (RNE), 1 instr for 2 elements
__device__ __forceinline__ unsigned cvtpk(float lo, float hi) {
    unsigned r;
    asm("v_cvt_pk_bf16_f32 %0, %1, %2" : "=v"(r) : "v"(lo), "v"(hi));
    return r;
}
__device__ __forceinline__ void ij_of(int p, int& i, int& j) {
    float s = sqrtf(8.0f * (float)p + 1.0f);
    i = (int)((s - 1.0f) * 0.5f);
    while ((i + 1) * (i + 2) / 2 <= p) ++i;
    while (i * (i + 1) / 2 > p) --i;
    j = p - i * (i + 1) / 2;
}
// h1 A-fragment: relu(unpack(u)+unpack(v)) packed to 8 bf16
__device__ __forceinline__ short8 buildA(uint4 uu, uint4 vv) {
    unsigned ua[4] = {uu.x, uu.y, uu.z, uu.w};
    unsigned va[4] = {vv.x, vv.y, vv.z, vv.w};
    union { unsigned u[4]; short8 s; } c;
    #pragma unroll
    for (int q = 0; q < 4; ++q) {
        float lo = asf(ua[q] << 16)         + asf(va[q] << 16);
        float hi = asf(ua[q] & 0xFFFF0000u) + asf(va[q] & 0xFFFF0000u);
        c.u[q] = cvtpk(fmaxf(lo, 0.f), fmaxf(hi, 0.f));
    }
    return c.s;
}
// same, returning raw uint4 (for LDS b128 store)
__device__ __forceinline__ uint4 build4(uint4 uu, uint4 vv) {
    union { uint4 v; short8 s; } c;
    c.s = buildA(uu, vv);
    return c.v;
}

// ---- fused preprocessing ------------------------------------------------
// grid (33, 8): x<32 -> U/V blocks; x==32 -> zero summed + transpose jobs
__global__ __launch_bounds__(256) void k_pre(
    const float* __restrict__ x, const float* __restrict__ code,
    const float* __restrict__ w1, const float* __restrict__ b1,
    const float* __restrict__ w2, const float* __restrict__ w3,
    unsigned short* __restrict__ ub, unsigned short* __restrict__ vb,
    unsigned short* __restrict__ w2t, unsigned short* __restrict__ w3t,
    float* __restrict__ summed)
{
    const int tid = threadIdx.x;
    if (blockIdx.x < 32) {
        const int ig = blockIdx.x, b = blockIdx.y, d = tid;
        float q = b1[d];
        const float* cp = code + b * 128;
        #pragma unroll 16
        for (int t = 0; t < 128; ++t) q += cp[t] * w1[(132 + t) * 256 + d];
        float su[8], sv[8];
        #pragma unroll
        for (int k = 0; k < 8; ++k) { su[k] = q; sv[k] = 0.f; }
        const float* xp = x + (b * 64) * 256 + ig * 8;
        #pragma unroll 8
        for (int c = 0; c < 64; ++c) {
            const float wu = w1[c * 256 + d];
            const float wv = w1[(66 + c) * 256 + d];
            const float* xc = xp + c * 256;          // uniform -> scalar loads
            #pragma unroll
            for (int k = 0; k < 8; ++k) { su[k] += xc[k] * wu; sv[k] += xc[k] * wv; }
        }
        const float wyu = w1[64 * 256 + d],  wxu = w1[65 * 256 + d];
        const float wyv = w1[130 * 256 + d], wxv = w1[131 * 256 + d];
        #pragma unroll
        for (int k = 0; k < 8; ++k) {
            const int i = ig * 8 + k;
            const float yy = (float)(i >> 4) * (2.0f / 15.0f) - 1.0f;
            const float xx = (float)(i & 15) * (2.0f / 15.0f) - 1.0f;
            ub[(b * 256 + i) * 256 + d] = f2bf(su[k] + yy * wyu + xx * wxu);
            vb[(b * 256 + i) * 256 + d] = f2bf(sv[k] + yy * wyv + xx * wxv);
        }
    } else {
        __shared__ float t[64][65];
        const int y = blockIdx.y;
        summed[y * 256 + tid] = 0.f;                 // re-zeroed every replay
        const int tx = tid & 63, ty = tid >> 6;
        for (int jj = 0; jj < 4; ++jj) {
            const int job = y * 4 + jj;              // 0..31
            const float* src = (job & 16) ? w3 : w2;
            unsigned short* dst = (job & 16) ? w3t : w2t;
            const int k0 = ((job >> 2) & 3) * 64, n0 = (job & 3) * 64;
            __syncthreads();
            #pragma unroll
            for (int r = ty; r < 64; r += 4) t[r][tx] = src[(k0 + r) * 256 + n0 + tx];
            __syncthreads();
            #pragma unroll
            for (int r = ty; r < 64; r += 4) dst[(n0 + r) * 256 + k0 + tx] = f2bf(t[tx][r]);
        }
    }
}

// ---- fused g_theta chain for 256 pairs (uniform full tiles) -------------
// Chunk swizzle everywhere: 16B chunk c of row r stored at chunk (c ^ (r&7)).
__global__ __launch_bounds__(512) void k_fuse(
    const unsigned short* __restrict__ ub, const unsigned short* __restrict__ vb,
    const unsigned short* __restrict__ w2t, const unsigned short* __restrict__ w3t,
    const float* __restrict__ b2, const float* __restrict__ b3,
    float* __restrict__ summed)
{
    extern __shared__ unsigned short lds[];        // 128 KiB
    const int tid  = threadIdx.x;
    const int pt   = blockIdx.x, b = blockIdx.y;
    const int lane = tid & 63, w = tid >> 6;
    const int lm   = lane & 15, quad = lane >> 4;

    // ---- stage W2^T[n][k] into LDS, chunk-swizzled ----
    #pragma unroll
    for (int it = 0; it < 16; ++it) {
        const int idx = it * 512 + tid;
        const int n = idx >> 5, c = idx & 31;
        const uint4 d = *(const uint4*)(w2t + n * 256 + c * 8);
        *(uint4*)(&lds[n * 256 + ((c ^ (n & 7)) << 3)]) = d;
    }

    // ---- GEMM1 row setup (wave owns rows w*32..w*32+31; always valid) ----
    const unsigned short* up[2];
    const unsigned short* vp[2];
    #pragma unroll
    for (int mt = 0; mt < 2; ++mt) {
        const int p = pt * 256 + w * 32 + mt * 16 + lm;   // < 32768 always
        int i, j; ij_of(p, i, j);
        up[mt] = ub + ((b * 256 + i) * 256) + quad * 8;
        vp[mt] = vb + ((b * 256 + j) * 256) + quad * 8;
    }
    __syncthreads();

    const float4v zero4 = {0.f, 0.f, 0.f, 0.f};

    // ---- GEMM1 (SWAPPED): acc1[nt][mt] = h2^T; A = W2frag (LDS),
    //      B = h1frag built in-reg from U/V (3-deep prefetch) ----
    float4v acc1[16][2];
    #pragma unroll
    for (int nt = 0; nt < 16; ++nt)
        #pragma unroll
        for (int mt = 0; mt < 2; ++mt) acc1[nt][mt] = zero4;
    {
        uint4 cu[3][2], cv[3][2];    // [slot][mt]
        #pragma unroll
        for (int kk = 0; kk < 3; ++kk)
            #pragma unroll
            for (int mt = 0; mt < 2; ++mt) {
                cu[kk][mt] = *(const uint4*)(up[mt] + kk * 32);
                cv[kk][mt] = *(const uint4*)(vp[mt] + kk * 32);
            }
        #pragma unroll
        for (int ks = 0; ks < 8; ++ks) {
            const int pr = ks % 3;
            short8 afr[2];
            #pragma unroll
            for (int mt = 0; mt < 2; ++mt) afr[mt] = buildA(cu[pr][mt], cv[pr][mt]);
            if (ks < 5) {
                #pragma unroll
                for (int mt = 0; mt < 2; ++mt) {
                    cu[pr][mt] = *(const uint4*)(up[mt] + (ks + 3) * 32);
                    cv[pr][mt] = *(const uint4*)(vp[mt] + (ks + 3) * 32);
                }
            }
            const int coff = ((ks * 4 + quad) ^ (lm & 7)) << 3;
            __builtin_amdgcn_s_setprio(1);
            #pragma unroll
            for (int ng = 0; ng < 4; ++ng) {
                short8 bfr[4];
                #pragma unroll
                for (int q = 0; q < 4; ++q)
                    bfr[q] = *(const short8*)(&lds[((ng * 4 + q) * 16 + lm) * 256 + coff]);
                #pragma unroll
                for (int q = 0; q < 4; ++q)
                    #pragma unroll
                    for (int mt = 0; mt < 2; ++mt)
                        acc1[ng * 4 + q][mt] = __builtin_amdgcn_mfma_f32_16x16x32_bf16(
                            bfr[q], afr[mt], acc1[ng * 4 + q][mt], 0, 0, 0);
            }
            __builtin_amdgcn_s_setprio(0);
        }
    }
    __syncthreads();   // all waves done reading W2 region

    // ---- hoist GEMM2 B-frags ks=0,1 (latency hidden under the scatter) --
    const unsigned short* bb3 = w3t + ((w * 32 + lm) * 256) + quad * 8;
    short8 bbuf[2][2];   // [parity][nt]
    #pragma unroll
    for (int kk = 0; kk < 2; ++kk)
        #pragma unroll
        for (int nt = 0; nt < 2; ++nt)
            bbuf[kk][nt] = *(const short8*)(bb3 + nt * 4096 + kk * 32);

    // ---- scatter h2 = relu(acc1+b2): acc is h2^T (lane lm = pair,
    //      n = nt*16 + quad*4 + rg) -> 32 ds_write_b64/thread ----
    #pragma unroll
    for (int nt = 0; nt < 16; ++nt) {
        const float4 bbv = *(const float4*)(b2 + nt * 16 + quad * 4);
        #pragma unroll
        for (int mt = 0; mt < 2; ++mt) {
            const int row = w * 32 + mt * 16 + lm;     // pair
            const float v0 = fmaxf(acc1[nt][mt][0] + bbv.x, 0.f);
            const float v1 = fmaxf(acc1[nt][mt][1] + bbv.y, 0.f);
            const float v2 = fmaxf(acc1[nt][mt][2] + bbv.z, 0.f);
            const float v3 = fmaxf(acc1[nt][mt][3] + bbv.w, 0.f);
            uint2 pk; pk.x = cvtpk(v0, v1); pk.y = cvtpk(v2, v3);
            const int c0 = nt * 2 + (quad >> 1);       // 16B chunk of n
            *(uint2*)(&lds[row * 256 + (((c0 ^ (row & 7)) << 3) | ((quad & 1) << 2))]) = pk;
        }
    }
    __syncthreads();

    // ---- GEMM2: rel = h2 @ W3, N-split (wave owns cols w*32..+31),
    //      A from LDS h2 tile, B = W3^T slice from L2 (2-deep prefetch) ----
    float4v acc2[16][2];
    #pragma unroll
    for (int mt = 0; mt < 16; ++mt)
        #pragma unroll
        for (int nt = 0; nt < 2; ++nt) acc2[mt][nt] = zero4;
    {
        for (int ks = 0; ks < 8; ++ks) {
            const int pr = ks & 1;
            short8 bcur[2];
            #pragma unroll
            for (int nt = 0; nt < 2; ++nt) bcur[nt] = bbuf[pr][nt];
            if (ks < 6) {
                #pragma unroll
                for (int nt = 0; nt < 2; ++nt)
                    bbuf[pr][nt] = *(const short8*)(bb3 + nt * 4096 + (ks + 2) * 32);
            }
            __builtin_amdgcn_s_setprio(1);
            #pragma unroll
            for (int mt = 0; mt < 16; ++mt) {
                const int row = mt * 16 + lm;
                const short8 a = *(const short8*)(
                    &lds[row * 256 + (((ks * 4 + quad) ^ (row & 7)) << 3)]);
                #pragma unroll
                for (int nt = 0; nt < 2; ++nt)
                    acc2[mt][nt] = __builtin_amdgcn_mfma_f32_16x16x32_bf16(
                        a, bcur[nt], acc2[mt][nt], 0, 0, 0);
            }
            __builtin_amdgcn_s_setprio(0);
        }
    }

    // ---- relu + column-sum over all 256 rows -> atomicAdd summed[b][col] ----
    #pragma unroll
    for (int nt = 0; nt < 2; ++nt) {
        const int col = w * 32 + nt * 16 + lm;
        const float bb = b3[col];
        float s = 0.f;
        #pragma unroll
        for (int mt = 0; mt < 16; ++mt)
            #pragma unroll
            for (int rg = 0; rg < 4; ++rg)
                s += fmaxf(acc2[mt][nt][rg] + bb, 0.f);
        s += __shfl_xor(s, 16);
        s += __shfl_xor(s, 32);
        if (quad == 0)
            atomicAdd(&summed[b * 256 + col], s);
    }
}

// ---- leftover 128 pairs (dieted) + f_phi --------------------------------
// 8 blocks (one per b) x 1024 threads (16 waves, 4pg x 4cg grid):
// wave = 32 pairs x 64 cols. h1 in LDS once; W2/W3 slices from L2 2-deep.
__global__ __launch_bounds__(1024) void k_tail(
    const unsigned short* __restrict__ ub, const unsigned short* __restrict__ vb,
    const unsigned short* __restrict__ w2t, const unsigned short* __restrict__ w3t,
    const float* __restrict__ b2, const float* __restrict__ b3,
    const float* __restrict__ summed,
    const float* __restrict__ fw1, const float* __restrict__ fb1,
    const float* __restrict__ fw2, const float* __restrict__ fb2,
    const float* __restrict__ fw3, const float* __restrict__ fb3,
    float* __restrict__ out)
{
    extern __shared__ unsigned short lds[];   // h1 64KiB | h2 64KiB | 7KiB f32
    unsigned short* h1t = lds;                // [128][256]
    unsigned short* h2t = lds + 32768;        // [128][256]
    float* ext = (float*)(lds + 65536);       // [256]
    float* s0  = ext + 256;                   // [256]
    float* s1  = s0 + 256;                    // [256]
    float* red = s1 + 256;                    // [1024]
    const int b = blockIdx.x, tid = threadIdx.x;
    const int lane = tid & 63, w = tid >> 6;  // 16 waves
    const int lm = lane & 15, quad = lane >> 4;
    const int pg = w >> 2, cg = w & 3;        // 4 pair-groups x 4 col-groups
    const float4v zero4 = {0.f, 0.f, 0.f, 0.f};

    if (tid < 256) ext[tid] = 0.f;

    // ---- build h1 rows 0..127 (pairs 32768..32895), 8 threads/row ----
    {
        const int r = tid >> 3, q8 = tid & 7;
        int i, j; ij_of(32768 + r, i, j);
        const unsigned short* up = ub + ((b * 256 + i) * 256) + q8 * 32;
        const unsigned short* vp = vb + ((b * 256 + j) * 256) + q8 * 32;
        const int rs = r & 7;
        #pragma unroll
        for (int it = 0; it < 4; ++it) {
            const uint4 uu = *(const uint4*)(up + it * 8);
            const uint4 vv = *(const uint4*)(vp + it * 8);
            const uint4 r4 = build4(uu, vv);
            const int chunk = q8 * 4 + it;
            *(uint4*)(&h1t[r * 256 + ((chunk ^ rs) << 3)]) = r4;
        }
    }
    // hoist GEMM1 W2-slice frags ks=0,1 (cover = build + barrier)
    const unsigned short* bb2 = w2t + ((cg * 64 + lm) * 256) + quad * 8;
    const unsigned short* bb3 = w3t + ((cg * 64 + lm) * 256) + quad * 8;
    short8 bbuf[2][4];
    #pragma unroll
    for (int kk = 0; kk < 2; ++kk)
        #pragma unroll
        for (int nt = 0; nt < 4; ++nt)
            bbuf[kk][nt] = *(const short8*)(bb2 + nt * 4096 + kk * 32);
    __syncthreads();

    // ---- GEMM1 (swapped): acc[nt][mt] = h2^T (pairs pg*32.., cols cg*64..)
    float4v acc[4][2];
    #pragma unroll
    for (int nt = 0; nt < 4; ++nt)
        #pragma unroll
        for (int mt = 0; mt < 2; ++mt) acc[nt][mt] = zero4;
    #pragma unroll
    for (int ks = 0; ks < 8; ++ks) {
        const int pr = ks & 1;
        short8 bcur[4];
        #pragma unroll
        for (int nt = 0; nt < 4; ++nt) bcur[nt] = bbuf[pr][nt];
        if (ks < 6) {
            #pragma unroll
            for (int nt = 0; nt < 4; ++nt)
                bbuf[pr][nt] = *(const short8*)(bb2 + nt * 4096 + (ks + 2) * 32);
        }
        const int coff = ((ks * 4 + quad) ^ (lm & 7)) << 3;
        short8 afr[2];
        #pragma unroll
        for (int mt = 0; mt < 2; ++mt)
            afr[mt] = *(const short8*)(&h1t[(pg * 32 + mt * 16 + lm) * 256 + coff]);
        #pragma unroll
        for (int nt = 0; nt < 4; ++nt)
            #pragma unroll
            for (int mt = 0; mt < 2; ++mt)
                acc[nt][mt] = __builtin_amdgcn_mfma_f32_16x16x32_bf16(
                    bcur[nt], afr[mt], acc[nt][mt], 0, 0, 0);
    }

    // hoist GEMM2 W3-slice frags ks=0,1 (cover = scatter + barrier)
    #pragma unroll
    for (int kk = 0; kk < 2; ++kk)
        #pragma unroll
        for (int nt = 0; nt < 4; ++nt)
            bbuf[kk][nt] = *(const short8*)(bb3 + nt * 4096 + kk * 32);

    // ---- scatter h2 = relu(acc+b2) into h2t (k_fuse-proven encoding) ----
    #pragma unroll
    for (int nt = 0; nt < 4; ++nt) {
        const float4 bbv = *(const float4*)(b2 + cg * 64 + nt * 16 + quad * 4);
        #pragma unroll
        for (int mt = 0; mt < 2; ++mt) {
            const int row = pg * 32 + mt * 16 + lm;    // pair row 0..127
            const float v0 = fmaxf(acc[nt][mt][0] + bbv.x, 0.f);
            const float v1 = fmaxf(acc[nt][mt][1] + bbv.y, 0.f);
            const float v2 = fmaxf(acc[nt][mt][2] + bbv.z, 0.f);
            const float v3 = fmaxf(acc[nt][mt][3] + bbv.w, 0.f);
            uint2 pk; pk.x = cvtpk(v0, v1); pk.y = cvtpk(v2, v3);
            const int c0 = cg * 8 + nt * 2 + (quad >> 1);  // 16B chunk of n
            *(uint2*)(&h2t[row * 256 +
                           (((c0 ^ (row & 7)) << 3) | ((quad & 1) << 2))]) = pk;
        }
    }
    __syncthreads();

    // ---- GEMM2 (normal): rel = h2 @ W3 (pairs pg*32.., cols cg*64..) ----
    float4v acc2[2][4];
    #pragma unroll
    for (int mt = 0; mt < 2; ++mt)
        #pragma unroll
        for (int nt = 0; nt < 4; ++nt) acc2[mt][nt] = zero4;
    #pragma unroll
    for (int ks = 0; ks < 8; ++ks) {
        const int pr = ks & 1;
        short8 bcur[4];
        #pragma unroll
        for (int nt = 0; nt < 4; ++nt) bcur[nt] = bbuf[pr][nt];
        if (ks < 6) {
            #pragma unroll
            for (int nt = 0; nt < 4; ++nt)
                bbuf[pr][nt] = *(const short8*)(bb3 + nt * 4096 + (ks + 2) * 32);
        }
        const int coff = ((ks * 4 + quad) ^ (lm & 7)) << 3;
        short8 afr[2];
        #pragma unroll
        for (int mt = 0; mt < 2; ++mt) {
            const int row = pg * 32 + mt * 16 + lm;
            afr[mt] = *(const short8*)(&h2t[row * 256 + coff]);
        }
        #pragma unroll
        for (int mt = 0; mt < 2; ++mt)
            #pragma unroll
            for (int nt = 0; nt < 4; ++nt)
                acc2[mt][nt] = __builtin_amdgcn_mfma_f32_16x16x32_bf16(
                    afr[mt], bcur[nt], acc2[mt][nt], 0, 0, 0);
    }

    // ---- relu + sum over this wave's 32 pairs -> LDS atomic into ext ----
    #pragma unroll
    for (int nt = 0; nt < 4; ++nt) {
        const int col = cg * 64 + nt * 16 + lm;
        const float bb = b3[col];
        float s = 0.f;
        #pragma unroll
        for (int mt = 0; mt < 2; ++mt)
            #pragma unroll
            for (int rg = 0; rg < 4; ++rg)
                s += fmaxf(acc2[mt][nt][rg] + bb, 0.f);
        s += __shfl_xor(s, 16);
        s += __shfl_xor(s, 32);
        if (quad == 0)
            atomicAdd(&ext[col], s);
    }
    __syncthreads();

    // ---- f_phi (fp32), 4-way k-split per 256-wide layer ----
    const int d = tid & 255, kh = tid >> 8;     // kh 0..3
    if (tid < 256) s0[tid] = summed[b * 256 + tid] + ext[tid];
    __syncthreads();
    float pk = 0.f;
    #pragma unroll 16
    for (int k = kh * 64; k < kh * 64 + 64; ++k) pk += s0[k] * fw1[k * 256 + d];
    red[kh * 256 + d] = pk;
    __syncthreads();
    if (tid < 256)
        s1[tid] = fmaxf(red[tid] + red[256 + tid] + red[512 + tid] + red[768 + tid]
                        + fb1[tid], 0.f);
    __syncthreads();
    pk = 0.f;
    #pragma unroll 16
    for (int k = kh * 64; k < kh * 64 + 64; ++k) pk += s1[k] * fw2[k * 256 + d];
    red[kh * 256 + d] = pk;
    __syncthreads();
    if (tid < 256)
        s0[tid] = fmaxf(red[tid] + red[256 + tid] + red[512 + tid] + red[768 + tid]
                        + fb2[tid], 0.f);
    __syncthreads();
    const int d3 = tid & 31, kh3 = tid >> 5;    // kh3 0..31
    pk = 0.f;
    #pragma unroll
    for (int k = kh3 * 8; k < kh3 * 8 + 8; ++k) pk += s0[k] * fw3[k * 32 + d3];
    red[kh3 * 32 + d3] = pk;
    __syncthreads();
    if (tid < 32) {
        float o = fb3[tid];
        #pragma unroll 8
        for (int r = 0; r < 32; ++r) o += red[r * 32 + tid];
        out[b * 32 + tid] = o;
    }
}

extern "C" void kernel_launch(void* const* d_in, const int* in_sizes, int n_in,
                              void* d_out, int out_size, void* d_ws, size_t ws_size,
                              hipStream_t stream) {
    const float* x    = (const float*)d_in[0];
    const float* code = (const float*)d_in[1];
    const float* gw1  = (const float*)d_in[2];
    const float* gb1  = (const float*)d_in[3];
    const float* gw2  = (const float*)d_in[4];
    const float* gb2  = (const float*)d_in[5];
    const float* gw3  = (const float*)d_in[6];
    const float* gb3  = (const float*)d_in[7];
    const float* fw1  = (const float*)d_in[8];
    const float* fb1  = (const float*)d_in[9];
    const float* fw2  = (const float*)d_in[10];
    const float* fb2  = (const float*)d_in[11];
    const float* fw3  = (const float*)d_in[12];
    const float* fb3  = (const float*)d_in[13];
    float* out = (float*)d_out;

    // workspace layout (bytes), total ~2.27 MB
    char* ws = (char*)d_ws;
    unsigned short* ub  = (unsigned short*)(ws);               // 1 MiB
    unsigned short* vb  = (unsigned short*)(ws + 1048576);     // 1 MiB
    unsigned short* w2t = (unsigned short*)(ws + 2097152);     // 128 KiB
    unsigned short* w3t = (unsigned short*)(ws + 2228224);     // 128 KiB
    float* summed = (float*)(ws + 2359296);                    // 8 KiB

    hipLaunchKernelGGL(k_pre, dim3(33, 8), dim3(256), 0, stream,
                       x, code, gw1, gb1, gw2, gw3, ub, vb, w2t, w3t, summed);
    hipLaunchKernelGGL(k_fuse, dim3(128, 8), dim3(512), 131072, stream,
                       ub, vb, w2t, w3t, gb2, gb3, summed);
    hipLaunchKernelGGL(k_tail, dim3(8), dim3(1024), 138240, stream,
                       ub, vb, w2t, w3t, gb2, gb3, summed,
                       fw1, fb1, fw2, fb2, fw3, fb3, out);
}